// Round 1
// baseline (422.234 us; speedup 1.0000x reference)
//
#include <hip/hip_runtime.h>
#include <math.h>

// Problem constants (fixed by the reference).
#define BB 32          // batch
#define MM 8192        // tokens
#define DD 256         // d_model
#define SCALE 0.0625f  // 1/sqrt(256)
#define WPB 128        // waves per batch  -> 64 tokens per wave
#define TPW (MM / WPB) // tokens per wave = 64
#define BLK_PER_B (WPB / 4)  // 4 waves per 256-thread block -> 32 blocks/batch

// ---------------------------------------------------------------------------
// Kernel 1: r[b,e] = SCALE * ((query[b] @ q_w^T + q_b) @ k_w)[e]
// k_b is dropped: it only adds a per-batch constant to the logits, which is
// softmax-invariant.
// ---------------------------------------------------------------------------
__global__ __launch_bounds__(256) void k_qr(
    const float* __restrict__ query, const float* __restrict__ q_w,
    const float* __restrict__ q_b, const float* __restrict__ k_w,
    float* __restrict__ r)
{
    const int b = blockIdx.x, tid = threadIdx.x;
    __shared__ float qv[DD];
    __shared__ float qp[DD];
    qv[tid] = query[b * DD + tid];
    __syncthreads();
    // qp[d] = query[b] . q_w[d,:] + q_b[d]   (thread tid == d)
    float acc = q_b[tid];
    const float* qwrow = q_w + (size_t)tid * DD;
    #pragma unroll 8
    for (int e = 0; e < DD; ++e) acc += qv[e] * qwrow[e];
    qp[tid] = acc;
    __syncthreads();
    // r[e] = sum_d qp[d] * k_w[d,e]          (thread tid == e, coalesced)
    float racc = 0.f;
    #pragma unroll 8
    for (int d = 0; d < DD; ++d) racc += qp[d] * k_w[d * DD + tid];
    r[b * DD + tid] = racc * SCALE;
}

// ---------------------------------------------------------------------------
// Kernel 2: flash-style single pass over tokens.
// Each wave owns TPW=64 consecutive tokens of one batch. Lane l holds
// elements [4l, 4l+4) of the 256-dim vectors. Per token: float4 load
// (1 KiB/wave, coalesced), dot with r, wave shuffle-reduce, online softmax,
// weighted accumulate of the raw token into u.
// ---------------------------------------------------------------------------
__global__ __launch_bounds__(256) void k_flash(
    const float* __restrict__ tokens, const float* __restrict__ r,
    float* __restrict__ part_m, float* __restrict__ part_l,
    float4* __restrict__ part_u)
{
    const int b    = blockIdx.y;
    const int blk  = blockIdx.x;          // 0..BLK_PER_B-1
    const int tid  = threadIdx.x;
    const int w    = tid >> 6;
    const int lane = tid & 63;
    const int wi   = blk * 4 + w;         // wave index within batch, 0..WPB-1
    const int m0   = wi * TPW;

    const float4* r4 = (const float4*)(r + b * DD);
    const float4 rr  = r4[lane];

    const float4* tok = (const float4*)tokens + ((size_t)b * MM + m0) * (DD / 4);

    float  mw = -INFINITY, lw = 0.f;
    float4 u  = make_float4(0.f, 0.f, 0.f, 0.f);

    for (int t = 0; t < TPW; t += 4) {
        float4 x0 = tok[(size_t)(t + 0) * (DD / 4) + lane];
        float4 x1 = tok[(size_t)(t + 1) * (DD / 4) + lane];
        float4 x2 = tok[(size_t)(t + 2) * (DD / 4) + lane];
        float4 x3 = tok[(size_t)(t + 3) * (DD / 4) + lane];

        float p0 = x0.x * rr.x + x0.y * rr.y + x0.z * rr.z + x0.w * rr.w;
        float p1 = x1.x * rr.x + x1.y * rr.y + x1.z * rr.z + x1.w * rr.w;
        float p2 = x2.x * rr.x + x2.y * rr.y + x2.z * rr.z + x2.w * rr.w;
        float p3 = x3.x * rr.x + x3.y * rr.y + x3.z * rr.z + x3.w * rr.w;

        // Interleaved 64-lane butterfly reductions (ILP across 4 tokens).
        #pragma unroll
        for (int o = 32; o > 0; o >>= 1) {
            p0 += __shfl_xor(p0, o);
            p1 += __shfl_xor(p1, o);
            p2 += __shfl_xor(p2, o);
            p3 += __shfl_xor(p3, o);
        }

        const float m4   = fmaxf(fmaxf(p0, p1), fmaxf(p2, p3));
        const float newm = fmaxf(mw, m4);
        const float alpha = __expf(mw - newm);   // exp(-inf)=0 on first iter
        const float w0 = __expf(p0 - newm);
        const float w1 = __expf(p1 - newm);
        const float w2 = __expf(p2 - newm);
        const float w3 = __expf(p3 - newm);
        lw = lw * alpha + (w0 + w1 + w2 + w3);
        u.x = u.x * alpha + w0 * x0.x + w1 * x1.x + w2 * x2.x + w3 * x3.x;
        u.y = u.y * alpha + w0 * x0.y + w1 * x1.y + w2 * x2.y + w3 * x3.y;
        u.z = u.z * alpha + w0 * x0.z + w1 * x1.z + w2 * x2.z + w3 * x3.z;
        u.w = u.w * alpha + w0 * x0.w + w1 * x1.w + w2 * x2.w + w3 * x3.w;
        mw = newm;
    }

    const int pi = b * WPB + wi;
    if (lane == 0) { part_m[pi] = mw; part_l[pi] = lw; }
    part_u[(size_t)pi * 64 + lane] = u;   // lane l -> elements [4l,4l+4)
}

// ---------------------------------------------------------------------------
// Kernel 3: combine WPB partials per batch, normalize, apply v_w / v_b.
// out[b,d] = sum_e (u[b,e]/l) * v_w[d,e] + v_b[d]
// ---------------------------------------------------------------------------
__global__ __launch_bounds__(256) void k_combine(
    const float* __restrict__ part_m, const float* __restrict__ part_l,
    const float* __restrict__ part_u, const float* __restrict__ v_w,
    const float* __restrict__ v_b, float* __restrict__ out)
{
    const int b = blockIdx.x, tid = threadIdx.x;
    __shared__ float red[256];
    __shared__ float sf[WPB];
    __shared__ float su[DD];

    // Global max over the WPB partial maxima.
    const float pm = (tid < WPB) ? part_m[b * WPB + tid] : -INFINITY;
    red[tid] = pm;
    __syncthreads();
    #pragma unroll
    for (int s = 128; s > 0; s >>= 1) {
        if (tid < s) red[tid] = fmaxf(red[tid], red[tid + s]);
        __syncthreads();
    }
    const float gm = red[0];
    __syncthreads();

    // Rescale factors and global denominator l.
    float lterm = 0.f;
    if (tid < WPB) {
        const float f = __expf(pm - gm);
        sf[tid] = f;
        lterm = part_l[b * WPB + tid] * f;
    }
    red[tid] = lterm;
    __syncthreads();
    #pragma unroll
    for (int s = 128; s > 0; s >>= 1) {
        if (tid < s) red[tid] += red[tid + s];
        __syncthreads();
    }
    const float l = red[0];

    // u[e] = sum_i part_u[b,i,e] * sf[i]   (thread tid == e, coalesced)
    float acc = 0.f;
    const float* pu = part_u + (size_t)b * WPB * DD;
    #pragma unroll 4
    for (int i = 0; i < WPB; ++i) acc += pu[i * DD + tid] * sf[i];
    su[tid] = acc / l;
    __syncthreads();

    // out[b,d] = su . v_w[d,:] + v_b[d]     (thread tid == d)
    float o = v_b[tid];
    const float* vrow = v_w + (size_t)tid * DD;
    #pragma unroll 8
    for (int e = 0; e < DD; ++e) o += su[e] * vrow[e];
    out[b * DD + tid] = o;
}

extern "C" void kernel_launch(void* const* d_in, const int* in_sizes, int n_in,
                              void* d_out, int out_size, void* d_ws, size_t ws_size,
                              hipStream_t stream) {
    const float* query  = (const float*)d_in[0];
    const float* tokens = (const float*)d_in[1];
    const float* q_w    = (const float*)d_in[2];
    const float* q_b    = (const float*)d_in[3];
    const float* k_w    = (const float*)d_in[4];
    // d_in[5] = k_b: softmax-invariant, unused.
    const float* v_w    = (const float*)d_in[6];
    const float* v_b    = (const float*)d_in[7];
    float* out = (float*)d_out;

    // Workspace layout (floats): r[32*256] | part_m[32*128] | part_l[32*128]
    //                            | part_u[32*128*256]   (~4.3 MB total)
    float* ws     = (float*)d_ws;
    float* r      = ws;
    float* part_m = r + BB * DD;
    float* part_l = part_m + BB * WPB;
    float* part_u = part_l + BB * WPB;   // 64 KiB offset -> float4 aligned

    k_qr<<<dim3(BB), dim3(256), 0, stream>>>(query, q_w, q_b, k_w, r);
    k_flash<<<dim3(BLK_PER_B, BB), dim3(256), 0, stream>>>(
        tokens, r, part_m, part_l, (float4*)part_u);
    k_combine<<<dim3(BB), dim3(256), 0, stream>>>(
        part_m, part_l, part_u, v_w, v_b, out);
}

// Round 2
// 399.511 us; speedup vs baseline: 1.0569x; 1.0569x over previous
//
#include <hip/hip_runtime.h>
#include <math.h>

// Problem constants (fixed by the reference).
#define BB 32          // batch
#define MM 8192        // tokens
#define DD 256         // d_model
#define SCALE 0.0625f  // 1/sqrt(256)
#define WPB 128        // waves per batch  -> 64 tokens per wave
#define TPW (MM / WPB) // tokens per wave = 64
#define BLK_PER_B (WPB / 4)  // 4 waves per 256-thread block -> 32 blocks/batch

using f4 = __attribute__((ext_vector_type(4))) float;

// ---------------------------------------------------------------------------
// Kernel 1: r[b,e] = SCALE * ((query[b] @ q_w^T + q_b) @ k_w)[e]
// k_b is dropped: it only adds a per-batch constant to the logits, which is
// softmax-invariant.
// ---------------------------------------------------------------------------
__global__ __launch_bounds__(256) void k_qr(
    const float* __restrict__ query, const float* __restrict__ q_w,
    const float* __restrict__ q_b, const float* __restrict__ k_w,
    float* __restrict__ r)
{
    const int b = blockIdx.x, tid = threadIdx.x;
    __shared__ float qv[DD];
    __shared__ float qp[DD];
    qv[tid] = query[b * DD + tid];
    __syncthreads();
    // qp[d] = query[b] . q_w[d,:] + q_b[d]   (thread tid == d)
    float acc = q_b[tid];
    const float* qwrow = q_w + (size_t)tid * DD;
    #pragma unroll 8
    for (int e = 0; e < DD; ++e) acc += qv[e] * qwrow[e];
    qp[tid] = acc;
    __syncthreads();
    // r[e] = sum_d qp[d] * k_w[d,e]          (thread tid == e, coalesced)
    float racc = 0.f;
    #pragma unroll 8
    for (int d = 0; d < DD; ++d) racc += qp[d] * k_w[d * DD + tid];
    r[b * DD + tid] = racc * SCALE;
}

// ---------------------------------------------------------------------------
// Kernel 2: flash-style single pass over tokens.
// Each wave owns TPW=64 consecutive tokens of one batch. Lane l holds
// elements [4l, 4l+4) of the 256-dim vectors. 8 tokens per iteration:
// nontemporal float4 loads (read-once stream), dot with r, 8-way-ILP
// 64-lane butterfly reduce, online softmax with wave-uniform rescale skip,
// weighted accumulate of the raw tokens into u.
// ---------------------------------------------------------------------------
__global__ __launch_bounds__(256) void k_flash(
    const float* __restrict__ tokens, const float* __restrict__ r,
    float* __restrict__ part_m, float* __restrict__ part_l,
    f4* __restrict__ part_u)
{
    const int b    = blockIdx.y;
    const int blk  = blockIdx.x;          // 0..BLK_PER_B-1
    const int tid  = threadIdx.x;
    const int w    = tid >> 6;
    const int lane = tid & 63;
    const int wi   = blk * 4 + w;         // wave index within batch, 0..WPB-1
    const int m0   = wi * TPW;

    const f4* r4 = (const f4*)(r + b * DD);
    const f4 rr  = r4[lane];

    const f4* tok = (const f4*)tokens + ((size_t)b * MM + m0) * (DD / 4) + lane;

    float mw = -INFINITY, lw = 0.f;
    f4 u = {0.f, 0.f, 0.f, 0.f};

    for (int t = 0; t < TPW; t += 8) {
        f4 x[8];
        #pragma unroll
        for (int j = 0; j < 8; ++j)
            x[j] = __builtin_nontemporal_load(tok + (size_t)(t + j) * (DD / 4));

        float p[8];
        #pragma unroll
        for (int j = 0; j < 8; ++j)
            p[j] = x[j].x * rr.x + x[j].y * rr.y + x[j].z * rr.z + x[j].w * rr.w;

        // 64-lane butterfly reductions, 8-way ILP.
        #pragma unroll
        for (int o = 32; o > 0; o >>= 1) {
            #pragma unroll
            for (int j = 0; j < 8; ++j)
                p[j] += __shfl_xor(p[j], o);
        }

        float m8 = p[0];
        #pragma unroll
        for (int j = 1; j < 8; ++j) m8 = fmaxf(m8, p[j]);

        // Wave-uniform (all lanes hold identical p/m after the reduce):
        // rescale only when the running max actually increases.
        if (m8 > mw) {
            const float alpha = __expf(mw - m8);   // exp(-inf)=0 on first iter
            mw = m8;
            lw *= alpha;
            u.x *= alpha; u.y *= alpha; u.z *= alpha; u.w *= alpha;
        }

        #pragma unroll
        for (int j = 0; j < 8; ++j) {
            const float wj = __expf(p[j] - mw);
            lw += wj;
            u.x += wj * x[j].x;
            u.y += wj * x[j].y;
            u.z += wj * x[j].z;
            u.w += wj * x[j].w;
        }
    }

    const int pi = b * WPB + wi;
    if (lane == 0) { part_m[pi] = mw; part_l[pi] = lw; }
    part_u[(size_t)pi * 64 + lane] = u;   // lane l -> elements [4l,4l+4)
}

// ---------------------------------------------------------------------------
// Kernel 3: combine WPB partials per batch, normalize, apply v_w / v_b.
// out[b,d] = sum_e (u[b,e]/l) * v_w[d,e] + v_b[d]
// ---------------------------------------------------------------------------
__global__ __launch_bounds__(256) void k_combine(
    const float* __restrict__ part_m, const float* __restrict__ part_l,
    const float* __restrict__ part_u, const float* __restrict__ v_w,
    const float* __restrict__ v_b, float* __restrict__ out)
{
    const int b = blockIdx.x, tid = threadIdx.x;
    __shared__ float red[256];
    __shared__ float sf[WPB];
    __shared__ float su[DD];

    // Global max over the WPB partial maxima.
    const float pm = (tid < WPB) ? part_m[b * WPB + tid] : -INFINITY;
    red[tid] = pm;
    __syncthreads();
    #pragma unroll
    for (int s = 128; s > 0; s >>= 1) {
        if (tid < s) red[tid] = fmaxf(red[tid], red[tid + s]);
        __syncthreads();
    }
    const float gm = red[0];
    __syncthreads();

    // Rescale factors and global denominator l.
    float lterm = 0.f;
    if (tid < WPB) {
        const float f = __expf(pm - gm);
        sf[tid] = f;
        lterm = part_l[b * WPB + tid] * f;
    }
    red[tid] = lterm;
    __syncthreads();
    #pragma unroll
    for (int s = 128; s > 0; s >>= 1) {
        if (tid < s) red[tid] += red[tid + s];
        __syncthreads();
    }
    const float l = red[0];

    // u[e] = sum_i part_u[b,i,e] * sf[i]   (thread tid == e, coalesced)
    float acc = 0.f;
    const float* pu = part_u + (size_t)b * WPB * DD;
    #pragma unroll 4
    for (int i = 0; i < WPB; ++i) acc += pu[i * DD + tid] * sf[i];
    su[tid] = acc / l;
    __syncthreads();

    // out[b,d] = su . v_w[d,:] + v_b[d]     (thread tid == d)
    float o = v_b[tid];
    const float* vrow = v_w + (size_t)tid * DD;
    #pragma unroll 8
    for (int e = 0; e < DD; ++e) o += su[e] * vrow[e];
    out[b * DD + tid] = o;
}

extern "C" void kernel_launch(void* const* d_in, const int* in_sizes, int n_in,
                              void* d_out, int out_size, void* d_ws, size_t ws_size,
                              hipStream_t stream) {
    const float* query  = (const float*)d_in[0];
    const float* tokens = (const float*)d_in[1];
    const float* q_w    = (const float*)d_in[2];
    const float* q_b    = (const float*)d_in[3];
    const float* k_w    = (const float*)d_in[4];
    // d_in[5] = k_b: softmax-invariant, unused.
    const float* v_w    = (const float*)d_in[6];
    const float* v_b    = (const float*)d_in[7];
    float* out = (float*)d_out;

    // Workspace layout (floats): r[32*256] | part_m[32*128] | part_l[32*128]
    //                            | part_u[32*128*256]   (~4.3 MB total)
    float* ws     = (float*)d_ws;
    float* r      = ws;
    float* part_m = r + BB * DD;
    float* part_l = part_m + BB * WPB;
    float* part_u = part_l + BB * WPB;   // 64 KiB offset -> float4 aligned

    k_qr<<<dim3(BB), dim3(256), 0, stream>>>(query, q_w, q_b, k_w, r);
    k_flash<<<dim3(BLK_PER_B, BB), dim3(256), 0, stream>>>(
        tokens, r, part_m, part_l, (f4*)part_u);
    k_combine<<<dim3(BB), dim3(256), 0, stream>>>(
        part_m, part_l, part_u, v_w, v_b, out);
}

// Round 3
// 398.001 us; speedup vs baseline: 1.0609x; 1.0038x over previous
//
#include <hip/hip_runtime.h>
#include <math.h>

// Problem constants (fixed by the reference).
#define BB 32          // batch
#define MM 8192        // tokens
#define DD 256         // d_model
#define SCALE 0.0625f  // 1/sqrt(256)
#define WPB 128        // waves per batch  -> 64 tokens per wave
#define TPW (MM / WPB) // tokens per wave = 64
#define BLK_PER_B (WPB / 4)  // 4 waves per 256-thread block -> 32 blocks/batch

using f4 = __attribute__((ext_vector_type(4))) float;

// ---------------------------------------------------------------------------
// Kernel 1: r[b,e] = SCALE * ((query[b] @ q_w^T + q_b) @ k_w)[e]
// k_b is dropped: it only adds a per-batch constant to the logits, which is
// softmax-invariant.
// ---------------------------------------------------------------------------
__global__ __launch_bounds__(256) void k_qr(
    const float* __restrict__ query, const float* __restrict__ q_w,
    const float* __restrict__ q_b, const float* __restrict__ k_w,
    float* __restrict__ r)
{
    const int b = blockIdx.x, tid = threadIdx.x;
    __shared__ float qv[DD];
    __shared__ float qp[DD];
    qv[tid] = query[b * DD + tid];
    __syncthreads();
    // qp[d] = query[b] . q_w[d,:] + q_b[d]   (thread tid == d)
    float acc = q_b[tid];
    const float* qwrow = q_w + (size_t)tid * DD;
    #pragma unroll 8
    for (int e = 0; e < DD; ++e) acc += qv[e] * qwrow[e];
    qp[tid] = acc;
    __syncthreads();
    // r[e] = sum_d qp[d] * k_w[d,e]          (thread tid == e, coalesced)
    float racc = 0.f;
    #pragma unroll 8
    for (int d = 0; d < DD; ++d) racc += qp[d] * k_w[d * DD + tid];
    r[b * DD + tid] = racc * SCALE;
}

// ---------------------------------------------------------------------------
// Kernel 2: flash-style single pass over tokens, 16-lane token groups.
// Lane l owns elements {4*(l&15) + 64c + i | c=0..3, i=0..3} of token
// m0 + 4*it + (l>>4).  One iteration = 4 tokens = 4 coalesced dwordx4 loads
// (each instruction covers 4 contiguous 256B chunks).  Logit reduction needs
// only shuffle offsets 1/2/4/8 (within 16-lane groups).  Each group keeps an
// independent branchless online-softmax state; merged across the 4 groups
// once at the end (offsets 16/32).  Next iteration's loads are prefetched
// into registers (software pipeline).
// ---------------------------------------------------------------------------
__global__ __launch_bounds__(256) void k_flash(
    const float* __restrict__ tokens, const float* __restrict__ r,
    float* __restrict__ part_m, float* __restrict__ part_l,
    f4* __restrict__ part_u)
{
    const int b    = blockIdx.y;
    const int blk  = blockIdx.x;          // 0..BLK_PER_B-1
    const int tid  = threadIdx.x;
    const int w    = tid >> 6;
    const int lane = tid & 63;
    const int g    = lane & 15;           // element-group position
    const int tg   = lane >> 4;           // token within 4-token subtile
    const int wi   = blk * 4 + w;         // wave index within batch, 0..WPB-1
    const int m0   = wi * TPW;

    // rr[c] matches the lane's element slice: elements [4g + 64c, +4)
    const f4* r4 = (const f4*)(r + b * DD);
    f4 rr[4];
    #pragma unroll
    for (int c = 0; c < 4; ++c) rr[c] = r4[16 * c + g];

    // f4 index of this lane's c=0 chunk of its token in subtile 0.
    const f4* tok = (const f4*)tokens + ((size_t)b * MM + m0) * (DD / 4)
                  + (size_t)tg * (DD / 4) + g;

    float mw = -INFINITY, lw = 0.f;
    f4 u[4] = {{0,0,0,0},{0,0,0,0},{0,0,0,0},{0,0,0,0}};

    // Software pipeline: prefetch subtile 0.
    f4 xn[4];
    #pragma unroll
    for (int c = 0; c < 4; ++c)
        xn[c] = __builtin_nontemporal_load(tok + 16 * c);

    const int NIT = TPW / 4;   // 16 iterations of 4 tokens
    for (int it = 0; it < NIT; ++it) {
        f4 x[4];
        #pragma unroll
        for (int c = 0; c < 4; ++c) x[c] = xn[c];

        if (it + 1 < NIT) {
            const f4* nxt = tok + (size_t)(it + 1) * 4 * (DD / 4);
            #pragma unroll
            for (int c = 0; c < 4; ++c)
                xn[c] = __builtin_nontemporal_load(nxt + 16 * c);
        }

        // Partial dot over this lane's 16 elements (4 independent sub-dots).
        float s0 = x[0].x*rr[0].x + x[0].y*rr[0].y + x[0].z*rr[0].z + x[0].w*rr[0].w;
        float s1 = x[1].x*rr[1].x + x[1].y*rr[1].y + x[1].z*rr[1].z + x[1].w*rr[1].w;
        float s2 = x[2].x*rr[2].x + x[2].y*rr[2].y + x[2].z*rr[2].z + x[2].w*rr[2].w;
        float s3 = x[3].x*rr[3].x + x[3].y*rr[3].y + x[3].z*rr[3].z + x[3].w*rr[3].w;
        float p  = (s0 + s1) + (s2 + s3);

        // Reduce within the 16-lane group (broadcasts the logit to all 16).
        p += __shfl_xor(p, 1);
        p += __shfl_xor(p, 2);
        p += __shfl_xor(p, 4);
        p += __shfl_xor(p, 8);

        // Branchless online softmax (state uniform within the group).
        const float newm  = fmaxf(mw, p);
        const float alpha = __expf(mw - newm);   // exp(-inf)=0 on first iter
        const float wj    = __expf(p  - newm);
        mw = newm;
        lw = lw * alpha + wj;
        #pragma unroll
        for (int c = 0; c < 4; ++c) {
            u[c].x = u[c].x * alpha + wj * x[c].x;
            u[c].y = u[c].y * alpha + wj * x[c].y;
            u[c].z = u[c].z * alpha + wj * x[c].z;
            u[c].w = u[c].w * alpha + wj * x[c].w;
        }
    }

    // Merge the 4 group-states across the wave (offsets 16, 32).
    float gm = mw;
    gm = fmaxf(gm, __shfl_xor(gm, 16));
    gm = fmaxf(gm, __shfl_xor(gm, 32));
    const float beta = __expf(mw - gm);
    float L = lw * beta;
    L += __shfl_xor(L, 16);
    L += __shfl_xor(L, 32);
    #pragma unroll
    for (int c = 0; c < 4; ++c) {
        u[c].x *= beta; u[c].y *= beta; u[c].z *= beta; u[c].w *= beta;
        u[c].x += __shfl_xor(u[c].x, 16);
        u[c].y += __shfl_xor(u[c].y, 16);
        u[c].z += __shfl_xor(u[c].z, 16);
        u[c].w += __shfl_xor(u[c].w, 16);
        u[c].x += __shfl_xor(u[c].x, 32);
        u[c].y += __shfl_xor(u[c].y, 32);
        u[c].z += __shfl_xor(u[c].z, 32);
        u[c].w += __shfl_xor(u[c].w, 32);
    }

    const int pi = b * WPB + wi;
    if (lane == 0) { part_m[pi] = gm; part_l[pi] = L; }
    // f4 slot j holds elements [4j, 4j+4): slot = 16c + g, so lane `lane`
    // writes u[lane>>4] to slot `lane` (branchless select avoids scratch).
    f4 val = u[0];
    val = (tg == 1) ? u[1] : val;
    val = (tg == 2) ? u[2] : val;
    val = (tg == 3) ? u[3] : val;
    part_u[(size_t)pi * 64 + lane] = val;
}

// ---------------------------------------------------------------------------
// Kernel 3: combine WPB partials per batch, normalize, apply v_w / v_b.
// out[b,d] = sum_e (u[b,e]/l) * v_w[d,e] + v_b[d]
// ---------------------------------------------------------------------------
__global__ __launch_bounds__(256) void k_combine(
    const float* __restrict__ part_m, const float* __restrict__ part_l,
    const float* __restrict__ part_u, const float* __restrict__ v_w,
    const float* __restrict__ v_b, float* __restrict__ out)
{
    const int b = blockIdx.x, tid = threadIdx.x;
    __shared__ float red[256];
    __shared__ float sf[WPB];
    __shared__ float su[DD];

    // Global max over the WPB partial maxima.
    const float pm = (tid < WPB) ? part_m[b * WPB + tid] : -INFINITY;
    red[tid] = pm;
    __syncthreads();
    #pragma unroll
    for (int s = 128; s > 0; s >>= 1) {
        if (tid < s) red[tid] = fmaxf(red[tid], red[tid + s]);
        __syncthreads();
    }
    const float gm = red[0];
    __syncthreads();

    // Rescale factors and global denominator l.
    float lterm = 0.f;
    if (tid < WPB) {
        const float f = __expf(pm - gm);
        sf[tid] = f;
        lterm = part_l[b * WPB + tid] * f;
    }
    red[tid] = lterm;
    __syncthreads();
    #pragma unroll
    for (int s = 128; s > 0; s >>= 1) {
        if (tid < s) red[tid] += red[tid + s];
        __syncthreads();
    }
    const float l = red[0];

    // u[e] = sum_i part_u[b,i,e] * sf[i]   (thread tid == e, coalesced)
    float acc = 0.f;
    const float* pu = part_u + (size_t)b * WPB * DD;
    #pragma unroll 4
    for (int i = 0; i < WPB; ++i) acc += pu[i * DD + tid] * sf[i];
    su[tid] = acc / l;
    __syncthreads();

    // out[b,d] = su . v_w[d,:] + v_b[d]     (thread tid == d)
    float o = v_b[tid];
    const float* vrow = v_w + (size_t)tid * DD;
    #pragma unroll 8
    for (int e = 0; e < DD; ++e) o += su[e] * vrow[e];
    out[b * DD + tid] = o;
}

extern "C" void kernel_launch(void* const* d_in, const int* in_sizes, int n_in,
                              void* d_out, int out_size, void* d_ws, size_t ws_size,
                              hipStream_t stream) {
    const float* query  = (const float*)d_in[0];
    const float* tokens = (const float*)d_in[1];
    const float* q_w    = (const float*)d_in[2];
    const float* q_b    = (const float*)d_in[3];
    const float* k_w    = (const float*)d_in[4];
    // d_in[5] = k_b: softmax-invariant, unused.
    const float* v_w    = (const float*)d_in[6];
    const float* v_b    = (const float*)d_in[7];
    float* out = (float*)d_out;

    // Workspace layout (floats): r[32*256] | part_m[32*128] | part_l[32*128]
    //                            | part_u[32*128*256]   (~4.3 MB total)
    float* ws     = (float*)d_ws;
    float* r      = ws;
    float* part_m = r + BB * DD;
    float* part_l = part_m + BB * WPB;
    float* part_u = part_l + BB * WPB;   // 64 KiB offset -> float4 aligned

    k_qr<<<dim3(BB), dim3(256), 0, stream>>>(query, q_w, q_b, k_w, r);
    k_flash<<<dim3(BLK_PER_B, BB), dim3(256), 0, stream>>>(
        tokens, r, part_m, part_l, (f4*)part_u);
    k_combine<<<dim3(BB), dim3(256), 0, stream>>>(
        part_m, part_l, part_u, v_w, v_b, out);
}